// Round 13
// baseline (203.749 us; speedup 1.0000x reference)
//
#include <hip/hip_runtime.h>
#include <math.h>
#include <stdint.h>

#define T_TOK 8192
#define HDIM 1024
#define IDIM 512
#define NEXP 8
#define NGRP 2
#define EPG 4

typedef unsigned short u16;
typedef __attribute__((ext_vector_type(8))) short short8;   // 8 bf16 in 4 VGPRs
typedef __attribute__((ext_vector_type(4))) float f32x4;

// async global->LDS, 16B per lane; LDS dest is wave-uniform base (HW adds lane*16)
#define GLD16(gp, lp) __builtin_amdgcn_global_load_lds(                        \
    (const __attribute__((address_space(1))) unsigned int*)(gp),               \
    (__attribute__((address_space(3))) unsigned int*)(lp), 16, 0, 0)

__device__ __forceinline__ u16 f2bf(float f) {  // RNE float->bf16
    unsigned int u = __float_as_uint(f);
    u += 0x7fffu + ((u >> 16) & 1u);
    return (u16)(u >> 16);
}
__device__ __forceinline__ float bf2f(u16 v) {
    return __uint_as_float(((unsigned int)v) << 16);
}

// 2D XCD chunking for the shared 8-col x 64-row GEMM grid geometry:
// xcd = bid&7 (round-robin dispatch), chunk = (row-half xcd>>2) x (col-pair xcd&3).
// A-replication 8 -> 4, B stays L2-resident per XCD.
__device__ __forceinline__ void xcd_decode(int bid, int& rowb, int& colb) {
    int xcd = bid & 7, widx = bid >> 3;
    colb = (xcd & 3) * 2 + (widx & 1);          // 0..7
    rowb = (xcd >> 2) * 32 + (widx >> 1);       // 0..63
}

// ---------------- prologue: router (blocks 0..2047) + weight transposes (2048..5503) ----------------
__global__ __launch_bounds__(256)
void prologue(const float* __restrict__ X,
              const float* __restrict__ Wr, const float* __restrict__ bias,
              u16* __restrict__ Xb, float* __restrict__ wpair, int* __restrict__ topk_ids,
              const float* __restrict__ wg,  const float* __restrict__ wu,
              const float* __restrict__ wdn, const float* __restrict__ swg,
              const float* __restrict__ swu, const float* __restrict__ swd,
              u16* __restrict__ wgT, u16* __restrict__ wuT, u16* __restrict__ wdnT,
              u16* __restrict__ swgT, u16* __restrict__ swuT, u16* __restrict__ swdT)
{
    __shared__ float tile[64][65];
    const int bid = blockIdx.x;

    if (bid < 2048) {
        // ---- router: one wave per token; no atomics ----
        int wave = threadIdx.x >> 6;
        int lane = threadIdx.x & 63;
        int t = bid * 4 + wave;

        float acc[NEXP];
#pragma unroll
        for (int e = 0; e < NEXP; ++e) acc[e] = 0.f;

        const float4* X4 = (const float4*)(X + (size_t)t * HDIM);
#pragma unroll
        for (int jj = 0; jj < 4; ++jj) {
            float4 xv = X4[lane + jj * 64];
            ushort4 bv;
            bv.x = f2bf(xv.x); bv.y = f2bf(xv.y); bv.z = f2bf(xv.z); bv.w = f2bf(xv.w);
            *(ushort4*)(Xb + (size_t)t * HDIM + (size_t)(lane + jj * 64) * 4) = bv;
#pragma unroll
            for (int e = 0; e < NEXP; ++e) {
                const float4* W4 = (const float4*)(Wr + (size_t)e * HDIM);
                float4 wv = W4[lane + jj * 64];
                acc[e] += xv.x * wv.x + xv.y * wv.y + xv.z * wv.z + xv.w * wv.w;
            }
        }
#pragma unroll
        for (int e = 0; e < NEXP; ++e) {
#pragma unroll
            for (int off = 32; off >= 1; off >>= 1)
                acc[e] += __shfl_xor(acc[e], off, 64);
        }

        if (lane == 0) {
            float s[NEXP], b[NEXP];
#pragma unroll
            for (int e = 0; e < NEXP; ++e) {
                s[e] = 1.f / (1.f + expf(-acc[e]));
                b[e] = s[e] + bias[e];
            }
            float gs[NGRP];
#pragma unroll
            for (int g = 0; g < NGRP; ++g) {
                float m1 = -1e30f, m2 = -1e30f;
#pragma unroll
                for (int j = 0; j < EPG; ++j) {
                    float v = b[g * EPG + j];
                    if (v > m1) { m2 = m1; m1 = v; }
                    else if (v > m2) { m2 = v; }
                }
                gs[g] = m1 + m2;
            }
            int bg = (gs[1] > gs[0]) ? 1 : 0;
            float masked[NEXP];
#pragma unroll
            for (int e = 0; e < NEXP; ++e)
                masked[e] = ((e >> 2) == bg) ? b[e] : 0.0f;
            int i0 = 0; float v0 = masked[0];
#pragma unroll
            for (int e = 1; e < NEXP; ++e)
                if (masked[e] > v0) { v0 = masked[e]; i0 = e; }
            int i1 = -1; float v1 = -1e30f;
#pragma unroll
            for (int e = 0; e < NEXP; ++e) {
                if (e == i0) continue;
                if (masked[e] > v1) { v1 = masked[e]; i1 = e; }
            }
            float w0 = s[i0], w1 = s[i1];
            float inv = 1.f / (w0 + w1 + 1e-20f);
            w0 *= inv; w1 *= inv;
            wpair[t * 2 + 0] = w0;
            wpair[t * 2 + 1] = w1;
            topk_ids[t] = i0 | (i1 << 8);
        }
        return;
    }

    // ---- transpose + fp32->bf16 convert: 27 matrices x 128 blocks ----
    int tb = bid - 2048;
    int m = tb >> 7;        // matrix id 0..26
    int i = tb & 127;
    const float* src; u16* dst; int R, C;
    const size_t EW = (size_t)HDIM * IDIM;
    if (m < 8)       { src = wg  + (size_t)m * EW;        dst = wgT  + (size_t)m * EW;        R = HDIM; C = IDIM; }
    else if (m < 16) { src = wu  + (size_t)(m - 8) * EW;  dst = wuT  + (size_t)(m - 8) * EW;  R = HDIM; C = IDIM; }
    else if (m < 24) { src = wdn + (size_t)(m - 16) * EW; dst = wdnT + (size_t)(m - 16) * EW; R = IDIM; C = HDIM; }
    else if (m == 24){ src = swg; dst = swgT; R = HDIM; C = IDIM; }
    else if (m == 25){ src = swu; dst = swuT; R = HDIM; C = IDIM; }
    else             { src = swd; dst = swdT; R = IDIM; C = HDIM; }
    int r0, c0;
    if (R == HDIM) { r0 = (i & 15) * 64; c0 = (i >> 4) * 64; }   // 16 x 8 blocks
    else           { r0 = (i & 7) * 64;  c0 = (i >> 3) * 64; }   // 8 x 16 blocks

    int t = threadIdx.x;
    int row = t >> 2;
#pragma unroll
    for (int j = 0; j < 4; ++j) {
        int c = ((t & 3) + j * 4) * 4;
        *(float4*)&tile[row][c] = *(const float4*)(src + (size_t)(r0 + row) * C + c0 + c);
    }
    __syncthreads();
    int c = t >> 2;
    int rchunk = (t & 3) * 16;
    __attribute__((aligned(16))) u16 pack[16];
#pragma unroll
    for (int k = 0; k < 16; ++k)
        pack[k] = f2bf(tile[rchunk + k][c]);
    uint4* d4 = (uint4*)(dst + (size_t)(c0 + c) * R + r0 + rchunk);
    d4[0] = *(uint4*)&pack[0];
    d4[1] = *(uint4*)&pack[8];
}

// ---------------- build per-expert pair lists (deterministic compaction) ----------------
__global__ __launch_bounds__(256)
void build_lists(const int* __restrict__ topk_ids,
                 int* __restrict__ counts,
                 int* __restrict__ pair_id)
{
    const int e = blockIdx.x;
    const int tid = threadIdx.x;
    const int lane = tid & 63;
    const int wid = tid >> 6;
    __shared__ int wsum[4];
    __shared__ int rb;
    if (tid == 0) rb = 0;
    __syncthreads();

    int* dst = pair_id + e * T_TOK;
    for (int c0 = 0; c0 < T_TOK; c0 += 256) {
        int t = c0 + tid;
        int ids = topk_ids[t];
        bool m0 = (ids & 0xff) == e;
        bool m1 = ((ids >> 8) & 0xff) == e;
        unsigned long long b0 = __ballot(m0);
        unsigned long long b1 = __ballot(m1);
        int n0 = __popcll(b0);
        int n1 = __popcll(b1);
        if (lane == 0) wsum[wid] = n0 + n1;
        __syncthreads();
        int pre = 0, tot = 0;
#pragma unroll
        for (int w = 0; w < 4; ++w) {
            int v = wsum[w];
            if (w < wid) pre += v;
            tot += v;
        }
        int mybase = rb + pre;
        unsigned long long ltmask = (lane == 63) ? ~0ull >> 1 : ((1ull << lane) - 1);
        if (m0) dst[mybase + __popcll(b0 & ltmask)] = t * 2;
        if (m1) dst[mybase + n0 + __popcll(b1 & ltmask)] = t * 2 + 1;
        __syncthreads();
        if (tid == 0) rb += tot;
    }
    __syncthreads();
    if (tid == 0) counts[e] = rb;
}

// ---------------- merged gate/up MFMA GEMM + SiLU -> h (bf16) ----------------
// Block tile 128x64(x2), BK=64, 32KB LDS, m97 schedule; 8 waves x (32x32) wave-tiles.
// Grid: 1D x=512 per z-slice; 2D XCD chunk decode.
__global__ __launch_bounds__(512)
void gateup_all(const u16* __restrict__ Xb,
                const u16* __restrict__ WgT, const u16* __restrict__ WuT,     // [E,I,H]
                const u16* __restrict__ sWgT, const u16* __restrict__ sWuT,   // [I,H]
                u16* __restrict__ hs,   // [T,I]
                u16* __restrict__ hp,   // [2T,I] contiguous per expert
                const int* __restrict__ counts,
                const int* __restrict__ pair_id)
{
    const int z = blockIdx.z;
    const bool SH = (z == 0);
    const int e = z - 1;
    const int nrows = SH ? T_TOK : counts[e];
    int rowb, colb;
    xcd_decode(blockIdx.x, rowb, colb);
    const int bm0 = rowb * 128;
    if (bm0 >= nrows) return;
    const int bn0 = colb * 64;
    const u16* wgT = SH ? sWgT : WgT + (size_t)e * HDIM * IDIM;
    const u16* wuT = SH ? sWuT : WuT + (size_t)e * HDIM * IDIM;
    const int* plist = SH ? nullptr : (pair_id + e * T_TOK);
    u16* hout = SH ? hs : hp;

    int ebase = 0;
    if (!SH) {
#pragma unroll
        for (int i = 0; i < NEXP; ++i) ebase += (i < e) ? counts[i] : 0;
    }

    __shared__ __attribute__((aligned(16))) short As[128 * 64];  // 16 KB
    __shared__ __attribute__((aligned(16))) short Bg[64 * 64];   // 8 KB
    __shared__ __attribute__((aligned(16))) short Bu[64 * 64];   // 8 KB

    const int tid = threadIdx.x;
    const int lane = tid & 63;
    const int wid = tid >> 6;           // 0..7

    const char* aptr[2];
#pragma unroll
    for (int i = 0; i < 2; ++i) {
        int g = wid * 2 + i;
        int r = g * 8 + (lane >> 3);
        int row = bm0 + r;
        int srow;
        if (SH) srow = row;
        else    srow = (row < nrows) ? (plist[row] >> 1) : 0;
        int cslot = ((lane & 7) ^ (r & 7)) * 8;
        aptr[i] = (const char*)(Xb + (size_t)srow * HDIM + cslot);
    }
    const char* bgptr; const char* buptr;
    {
        int r = wid * 8 + (lane >> 3);
        int nn = bn0 + r;
        int cslot = ((lane & 7) ^ (r & 7)) * 8;
        bgptr = (const char*)(wgT + (size_t)nn * HDIM + cslot);
        buptr = (const char*)(wuT + (size_t)nn * HDIM + cslot);
    }

    const int wm = wid & 3, wn = wid >> 2;    // 4 M-tiles x 2 N-tiles
    const int m0 = wm * 32, n0 = wn * 32;
    const int lr = lane & 15, lg = lane >> 4;

    f32x4 accg[2][2] = {};
    f32x4 accu[2][2] = {};

    for (int k0 = 0; k0 < HDIM; k0 += 64) {
#pragma unroll
        for (int i = 0; i < 2; ++i) {
            GLD16(aptr[i], (char*)As + (wid * 2 + i) * 1024);
            aptr[i] += 128;
        }
        GLD16(bgptr, (char*)Bg + wid * 1024);
        GLD16(buptr, (char*)Bu + wid * 1024);
        bgptr += 128; buptr += 128;
        __syncthreads();
#pragma unroll
        for (int kk = 0; kk < 2; ++kk) {
            short8 af[2], bgf[2], buf_[2];
#pragma unroll
            for (int mf = 0; mf < 2; ++mf) {
                int row = m0 + mf * 16 + lr;
                int slot = (kk * 4 + lg) ^ (row & 7);
                af[mf] = *(const short8*)((const char*)As + row * 128 + slot * 16);
            }
#pragma unroll
            for (int nf = 0; nf < 2; ++nf) {
                int row = n0 + nf * 16 + lr;
                int slot = (kk * 4 + lg) ^ (row & 7);
                bgf[nf]  = *(const short8*)((const char*)Bg + row * 128 + slot * 16);
                buf_[nf] = *(const short8*)((const char*)Bu + row * 128 + slot * 16);
            }
#pragma unroll
            for (int mf = 0; mf < 2; ++mf)
#pragma unroll
                for (int nf = 0; nf < 2; ++nf) {
                    accg[mf][nf] = __builtin_amdgcn_mfma_f32_16x16x32_bf16(af[mf], bgf[nf],  accg[mf][nf], 0, 0, 0);
                    accu[mf][nf] = __builtin_amdgcn_mfma_f32_16x16x32_bf16(af[mf], buf_[nf], accu[mf][nf], 0, 0, 0);
                }
        }
        __syncthreads();
    }

    // epilogue: C/D layout col=lane&15, row=4*(lane>>4)+reg
#pragma unroll
    for (int mf = 0; mf < 2; ++mf) {
#pragma unroll
        for (int j = 0; j < 4; ++j) {
            int row = bm0 + m0 + mf * 16 + lg * 4 + j;
            if (row >= nrows) continue;
            int outrow = SH ? row : (ebase + row);   // contiguous per expert
            u16* dst = hout + (size_t)outrow * IDIM + bn0 + n0 + lr;
#pragma unroll
            for (int nf = 0; nf < 2; ++nf) {
                float g = accg[mf][nf][j], u = accu[mf][nf][j];
                float sg = g / (1.f + __expf(-g));
                dst[nf * 16] = f2bf(sg * u);
            }
        }
    }
}

// ---------------- routed down: contiguous A rows; slot0 -> y0, slot1 -> y1 (bf16) ----------------
// Block tile 128x128, 8 waves x (32x64) wave-tiles; 2D XCD chunk decode.
__global__ __launch_bounds__(512)
void down_routed(const u16* __restrict__ Hp,      // [2T,I] contiguous per expert
                 const u16* __restrict__ WdT,     // [E,H,I]
                 u16* __restrict__ y0,            // [T,H]
                 u16* __restrict__ y1,            // [T,H]
                 const float* __restrict__ wpair,
                 const int* __restrict__ counts,
                 const int* __restrict__ pair_id)
{
    const int e = blockIdx.z;
    const int nrows = counts[e];
    int rowb, colb;
    xcd_decode(blockIdx.x, rowb, colb);
    const int bm0 = rowb * 128;
    if (bm0 >= nrows) return;
    const int bn0 = colb * 128;
    const u16* wdT = WdT + (size_t)e * HDIM * IDIM;
    const int* plist = pair_id + e * T_TOK;

    int ebase = 0;
#pragma unroll
    for (int i = 0; i < NEXP; ++i) ebase += (i < e) ? counts[i] : 0;

    __shared__ __attribute__((aligned(16))) short As[128 * 64];  // 16 KB
    __shared__ __attribute__((aligned(16))) short Bs[128 * 64];  // 16 KB

    const int tid = threadIdx.x;
    const int lane = tid & 63;
    const int wid = tid >> 6;

    const char* aptr[2]; const char* bptr[2];
#pragma unroll
    for (int i = 0; i < 2; ++i) {
        int g = wid * 2 + i;
        int r = g * 8 + (lane >> 3);
        int row = bm0 + r;
        int srow = ebase + ((row < nrows) ? row : 0);   // contiguous stream
        int cslot = ((lane & 7) ^ (r & 7)) * 8;
        aptr[i] = (const char*)(Hp + (size_t)srow * IDIM + cslot);
        bptr[i] = (const char*)(wdT + (size_t)(bn0 + r) * IDIM + cslot);
    }

    const int wm = wid & 3, wn = wid >> 2;    // 4 M-tiles x 2 N-tiles
    const int m0 = wm * 32, n0 = wn * 64;
    const int lr = lane & 15, lg = lane >> 4;

    f32x4 acc[2][4] = {};

    for (int k0 = 0; k0 < IDIM; k0 += 64) {
#pragma unroll
        for (int i = 0; i < 2; ++i) {
            GLD16(aptr[i], (char*)As + (wid * 2 + i) * 1024);
            GLD16(bptr[i], (char*)Bs + (wid * 2 + i) * 1024);
            aptr[i] += 128; bptr[i] += 128;
        }
        __syncthreads();
#pragma unroll
        for (int kk = 0; kk < 2; ++kk) {
            short8 af[2], bf[4];
#pragma unroll
            for (int mf = 0; mf < 2; ++mf) {
                int row = m0 + mf * 16 + lr;
                int slot = (kk * 4 + lg) ^ (row & 7);
                af[mf] = *(const short8*)((const char*)As + row * 128 + slot * 16);
            }
#pragma unroll
            for (int nf = 0; nf < 4; ++nf) {
                int row = n0 + nf * 16 + lr;
                int slot = (kk * 4 + lg) ^ (row & 7);
                bf[nf] = *(const short8*)((const char*)Bs + row * 128 + slot * 16);
            }
#pragma unroll
            for (int mf = 0; mf < 2; ++mf)
#pragma unroll
                for (int nf = 0; nf < 4; ++nf)
                    acc[mf][nf] = __builtin_amdgcn_mfma_f32_16x16x32_bf16(af[mf], bf[nf], acc[mf][nf], 0, 0, 0);
        }
        __syncthreads();
    }

#pragma unroll
    for (int mf = 0; mf < 2; ++mf) {
#pragma unroll
        for (int j = 0; j < 4; ++j) {
            int row = bm0 + m0 + mf * 16 + lg * 4 + j;
            if (row >= nrows) continue;
            int p = plist[row];
            int t = p >> 1;
            float w = wpair[p];
            u16* dst = ((p & 1) ? y1 : y0) + (size_t)t * HDIM + bn0 + n0 + lr;
#pragma unroll
            for (int nf = 0; nf < 4; ++nf)
                dst[nf * 16] = f2bf(acc[mf][nf][j] * w);
        }
    }
}

// ---------------- shared down + combine: out = hs@swd + y0 + y1 (write-only out) ----------------
__global__ __launch_bounds__(512)
void down_shared_combine(const u16* __restrict__ Hs,   // [T,I]
                         const u16* __restrict__ swdT, // [H,I]
                         const u16* __restrict__ y0,   // [T,H]
                         const u16* __restrict__ y1,   // [T,H]
                         float* __restrict__ out)      // [T,H]
{
    int rowb, colb;
    xcd_decode(blockIdx.x, rowb, colb);
    const int bm0 = rowb * 128;
    const int bn0 = colb * 128;

    __shared__ __attribute__((aligned(16))) short As[128 * 64];
    __shared__ __attribute__((aligned(16))) short Bs[128 * 64];

    const int tid = threadIdx.x;
    const int lane = tid & 63;
    const int wid = tid >> 6;

    const char* aptr[2]; const char* bptr[2];
#pragma unroll
    for (int i = 0; i < 2; ++i) {
        int g = wid * 2 + i;
        int r = g * 8 + (lane >> 3);
        int cslot = ((lane & 7) ^ (r & 7)) * 8;
        aptr[i] = (const char*)(Hs + (size_t)(bm0 + r) * IDIM + cslot);
        bptr[i] = (const char*)(swdT + (size_t)(bn0 + r) * IDIM + cslot);
    }

    const int wm = wid & 3, wn = wid >> 2;
    const int m0 = wm * 32, n0 = wn * 64;
    const int lr = lane & 15, lg = lane >> 4;

    f32x4 acc[2][4] = {};

    for (int k0 = 0; k0 < IDIM; k0 += 64) {
#pragma unroll
        for (int i = 0; i < 2; ++i) {
            GLD16(aptr[i], (char*)As + (wid * 2 + i) * 1024);
            GLD16(bptr[i], (char*)Bs + (wid * 2 + i) * 1024);
            aptr[i] += 128; bptr[i] += 128;
        }
        __syncthreads();
#pragma unroll
        for (int kk = 0; kk < 2; ++kk) {
            short8 af[2], bf[4];
#pragma unroll
            for (int mf = 0; mf < 2; ++mf) {
                int row = m0 + mf * 16 + lr;
                int slot = (kk * 4 + lg) ^ (row & 7);
                af[mf] = *(const short8*)((const char*)As + row * 128 + slot * 16);
            }
#pragma unroll
            for (int nf = 0; nf < 4; ++nf) {
                int row = n0 + nf * 16 + lr;
                int slot = (kk * 4 + lg) ^ (row & 7);
                bf[nf] = *(const short8*)((const char*)Bs + row * 128 + slot * 16);
            }
#pragma unroll
            for (int mf = 0; mf < 2; ++mf)
#pragma unroll
                for (int nf = 0; nf < 4; ++nf)
                    acc[mf][nf] = __builtin_amdgcn_mfma_f32_16x16x32_bf16(af[mf], bf[nf], acc[mf][nf], 0, 0, 0);
        }
        __syncthreads();
    }

#pragma unroll
    for (int mf = 0; mf < 2; ++mf) {
#pragma unroll
        for (int j = 0; j < 4; ++j) {
            int t = bm0 + m0 + mf * 16 + lg * 4 + j;
            float* dst = out + (size_t)t * HDIM + bn0 + n0 + lr;
            const u16* y0src = y0 + (size_t)t * HDIM + bn0 + n0 + lr;
            const u16* y1src = y1 + (size_t)t * HDIM + bn0 + n0 + lr;
#pragma unroll
            for (int nf = 0; nf < 4; ++nf)
                dst[nf * 16] = acc[mf][nf][j] + bf2f(y0src[nf * 16]) + bf2f(y1src[nf * 16]);
        }
    }
}

extern "C" void kernel_launch(void* const* d_in, const int* in_sizes, int n_in,
                              void* d_out, int out_size, void* d_ws, size_t ws_size,
                              hipStream_t stream) {
    const float* X    = (const float*)d_in[0];
    const float* Wr   = (const float*)d_in[1];
    const float* bias = (const float*)d_in[2];
    const float* wg   = (const float*)d_in[3];
    const float* wu   = (const float*)d_in[4];
    const float* wdn  = (const float*)d_in[5];
    const float* swg  = (const float*)d_in[6];
    const float* swu  = (const float*)d_in[7];
    const float* swd  = (const float*)d_in[8];
    float* out = (float*)d_out;
    (void)in_sizes; (void)n_in; (void)out_size; (void)ws_size;

    char* ws = (char*)d_ws;
    const size_t MB = 1048576;
    int*   counts   = (int*)ws;                          // 32 B
    float* wpair    = (float*)(ws + 4096);               // 64 KB
    int*   pair_id  = (int*)(ws + 4096 + 65536);         // 256 KB
    int*   topk_ids = (int*)(ws + 524288);               // 32 KB
    u16* Xb   = (u16*)(ws + 1 * MB);                     // 16 MB [T,H]; y1 aliases after gateup
    u16* wgT  = (u16*)(ws + 17 * MB);                    // 8 MB [E,I,H]; y0 aliases wgT+wuT after gateup
    u16* wuT  = (u16*)(ws + 25 * MB);                    // 8 MB
    u16* wdnT = (u16*)(ws + 33 * MB);                    // 8 MB [E,H,I]
    u16* swgT = (u16*)(ws + 41 * MB);                    // 1 MB [I,H]
    u16* swuT = (u16*)(ws + 42 * MB);                    // 1 MB
    u16* swdT = (u16*)(ws + 43 * MB);                    // 1 MB [H,I]
    u16* hs   = (u16*)(ws + 44 * MB);                    // 8 MB [T,I]
    u16* hp   = (u16*)(ws + 52 * MB);                    // 16 MB [2T,I] contiguous per expert
    u16* y1   = Xb;                                      // Xb dead after gateup_all
    u16* y0   = wgT;                                     // wgT/wuT dead after gateup_all (16 MB span)

    // router (2048 blocks) + 27 weight transposes (3456 blocks) in one launch
    prologue<<<2048 + 27 * 128, 256, 0, stream>>>(
        X, Wr, bias, Xb, wpair, topk_ids,
        wg, wu, wdn, swg, swu, swd, wgT, wuT, wdnT, swgT, swuT, swdT);
    build_lists<<<NEXP, 256, 0, stream>>>(topk_ids, counts, pair_id);

    // 1D x-grid per z-slice; 2D XCD chunking (row-half x col-pair) inside
    gateup_all<<<dim3(512, 1, NEXP + 1), 512, 0, stream>>>(
        Xb, wgT, wuT, swgT, swuT, hs, hp, counts, pair_id);

    down_routed<<<dim3(512, 1, NEXP), 512, 0, stream>>>(
        hp, wdnT, y0, y1, wpair, counts, pair_id);

    down_shared_combine<<<dim3(512, 1, 1), 512, 0, stream>>>(
        hs, swdT, y0, y1, out);
}

// Round 14
// 169.403 us; speedup vs baseline: 1.2027x; 1.2027x over previous
//
#include <hip/hip_runtime.h>
#include <math.h>
#include <stdint.h>

#define T_TOK 8192
#define HDIM 1024
#define IDIM 512
#define NEXP 8
#define NGRP 2
#define EPG 4

typedef unsigned short u16;
typedef __attribute__((ext_vector_type(8))) short short8;   // 8 bf16 in 4 VGPRs
typedef __attribute__((ext_vector_type(4))) float f32x4;

// async global->LDS, 16B per lane; LDS dest is wave-uniform base (HW adds lane*16)
#define GLD16(gp, lp) __builtin_amdgcn_global_load_lds(                        \
    (const __attribute__((address_space(1))) unsigned int*)(gp),               \
    (__attribute__((address_space(3))) unsigned int*)(lp), 16, 0, 0)

__device__ __forceinline__ u16 f2bf(float f) {  // RNE float->bf16
    unsigned int u = __float_as_uint(f);
    u += 0x7fffu + ((u >> 16) & 1u);
    return (u16)(u >> 16);
}
__device__ __forceinline__ float bf2f(u16 v) {
    return __uint_as_float(((unsigned int)v) << 16);
}

// ---------------- prologue: router (blocks 0..2047) + weight transposes (2048..5503) ----------------
__global__ __launch_bounds__(256)
void prologue(const float* __restrict__ X,
              const float* __restrict__ Wr, const float* __restrict__ bias,
              u16* __restrict__ Xb, float* __restrict__ wpair, int* __restrict__ topk_ids,
              const float* __restrict__ wg,  const float* __restrict__ wu,
              const float* __restrict__ wdn, const float* __restrict__ swg,
              const float* __restrict__ swu, const float* __restrict__ swd,
              u16* __restrict__ wgT, u16* __restrict__ wuT, u16* __restrict__ wdnT,
              u16* __restrict__ swgT, u16* __restrict__ swuT, u16* __restrict__ swdT)
{
    __shared__ float tile[64][65];
    const int bid = blockIdx.x;

    if (bid < 2048) {
        // ---- router: one wave per token; no atomics ----
        int wave = threadIdx.x >> 6;
        int lane = threadIdx.x & 63;
        int t = bid * 4 + wave;

        float acc[NEXP];
#pragma unroll
        for (int e = 0; e < NEXP; ++e) acc[e] = 0.f;

        const float4* X4 = (const float4*)(X + (size_t)t * HDIM);
#pragma unroll
        for (int jj = 0; jj < 4; ++jj) {
            float4 xv = X4[lane + jj * 64];
            ushort4 bv;
            bv.x = f2bf(xv.x); bv.y = f2bf(xv.y); bv.z = f2bf(xv.z); bv.w = f2bf(xv.w);
            *(ushort4*)(Xb + (size_t)t * HDIM + (size_t)(lane + jj * 64) * 4) = bv;
#pragma unroll
            for (int e = 0; e < NEXP; ++e) {
                const float4* W4 = (const float4*)(Wr + (size_t)e * HDIM);
                float4 wv = W4[lane + jj * 64];
                acc[e] += xv.x * wv.x + xv.y * wv.y + xv.z * wv.z + xv.w * wv.w;
            }
        }
#pragma unroll
        for (int e = 0; e < NEXP; ++e) {
#pragma unroll
            for (int off = 32; off >= 1; off >>= 1)
                acc[e] += __shfl_xor(acc[e], off, 64);
        }

        if (lane == 0) {
            float s[NEXP], b[NEXP];
#pragma unroll
            for (int e = 0; e < NEXP; ++e) {
                s[e] = 1.f / (1.f + expf(-acc[e]));
                b[e] = s[e] + bias[e];
            }
            float gs[NGRP];
#pragma unroll
            for (int g = 0; g < NGRP; ++g) {
                float m1 = -1e30f, m2 = -1e30f;
#pragma unroll
                for (int j = 0; j < EPG; ++j) {
                    float v = b[g * EPG + j];
                    if (v > m1) { m2 = m1; m1 = v; }
                    else if (v > m2) { m2 = v; }
                }
                gs[g] = m1 + m2;
            }
            int bg = (gs[1] > gs[0]) ? 1 : 0;
            float masked[NEXP];
#pragma unroll
            for (int e = 0; e < NEXP; ++e)
                masked[e] = ((e >> 2) == bg) ? b[e] : 0.0f;
            int i0 = 0; float v0 = masked[0];
#pragma unroll
            for (int e = 1; e < NEXP; ++e)
                if (masked[e] > v0) { v0 = masked[e]; i0 = e; }
            int i1 = -1; float v1 = -1e30f;
#pragma unroll
            for (int e = 0; e < NEXP; ++e) {
                if (e == i0) continue;
                if (masked[e] > v1) { v1 = masked[e]; i1 = e; }
            }
            float w0 = s[i0], w1 = s[i1];
            float inv = 1.f / (w0 + w1 + 1e-20f);
            w0 *= inv; w1 *= inv;
            wpair[t * 2 + 0] = w0;
            wpair[t * 2 + 1] = w1;
            topk_ids[t] = i0 | (i1 << 8);
        }
        return;
    }

    // ---- transpose + fp32->bf16 convert: 27 matrices x 128 blocks ----
    int tb = bid - 2048;
    int m = tb >> 7;        // matrix id 0..26
    int i = tb & 127;
    const float* src; u16* dst; int R, C;
    const size_t EW = (size_t)HDIM * IDIM;
    if (m < 8)       { src = wg  + (size_t)m * EW;        dst = wgT  + (size_t)m * EW;        R = HDIM; C = IDIM; }
    else if (m < 16) { src = wu  + (size_t)(m - 8) * EW;  dst = wuT  + (size_t)(m - 8) * EW;  R = HDIM; C = IDIM; }
    else if (m < 24) { src = wdn + (size_t)(m - 16) * EW; dst = wdnT + (size_t)(m - 16) * EW; R = IDIM; C = HDIM; }
    else if (m == 24){ src = swg; dst = swgT; R = HDIM; C = IDIM; }
    else if (m == 25){ src = swu; dst = swuT; R = HDIM; C = IDIM; }
    else             { src = swd; dst = swdT; R = IDIM; C = HDIM; }
    int r0, c0;
    if (R == HDIM) { r0 = (i & 15) * 64; c0 = (i >> 4) * 64; }   // 16 x 8 blocks
    else           { r0 = (i & 7) * 64;  c0 = (i >> 3) * 64; }   // 8 x 16 blocks

    int t = threadIdx.x;
    int row = t >> 2;
#pragma unroll
    for (int j = 0; j < 4; ++j) {
        int c = ((t & 3) + j * 4) * 4;
        *(float4*)&tile[row][c] = *(const float4*)(src + (size_t)(r0 + row) * C + c0 + c);
    }
    __syncthreads();
    int c = t >> 2;
    int rchunk = (t & 3) * 16;
    __attribute__((aligned(16))) u16 pack[16];
#pragma unroll
    for (int k = 0; k < 16; ++k)
        pack[k] = f2bf(tile[rchunk + k][c]);
    uint4* d4 = (uint4*)(dst + (size_t)(c0 + c) * R + r0 + rchunk);
    d4[0] = *(uint4*)&pack[0];
    d4[1] = *(uint4*)&pack[8];
}

// ---------------- build per-expert pair lists (deterministic compaction) ----------------
__global__ __launch_bounds__(256)
void build_lists(const int* __restrict__ topk_ids,
                 int* __restrict__ counts,
                 int* __restrict__ pair_id)
{
    const int e = blockIdx.x;
    const int tid = threadIdx.x;
    const int lane = tid & 63;
    const int wid = tid >> 6;
    __shared__ int wsum[4];
    __shared__ int rb;
    if (tid == 0) rb = 0;
    __syncthreads();

    int* dst = pair_id + e * T_TOK;
    for (int c0 = 0; c0 < T_TOK; c0 += 256) {
        int t = c0 + tid;
        int ids = topk_ids[t];
        bool m0 = (ids & 0xff) == e;
        bool m1 = ((ids >> 8) & 0xff) == e;
        unsigned long long b0 = __ballot(m0);
        unsigned long long b1 = __ballot(m1);
        int n0 = __popcll(b0);
        int n1 = __popcll(b1);
        if (lane == 0) wsum[wid] = n0 + n1;
        __syncthreads();
        int pre = 0, tot = 0;
#pragma unroll
        for (int w = 0; w < 4; ++w) {
            int v = wsum[w];
            if (w < wid) pre += v;
            tot += v;
        }
        int mybase = rb + pre;
        unsigned long long ltmask = (lane == 63) ? ~0ull >> 1 : ((1ull << lane) - 1);
        if (m0) dst[mybase + __popcll(b0 & ltmask)] = t * 2;
        if (m1) dst[mybase + n0 + __popcll(b1 & ltmask)] = t * 2 + 1;
        __syncthreads();
        if (tid == 0) rb += tot;
    }
    __syncthreads();
    if (tid == 0) counts[e] = rb;
}

// ---------------- merged gate/up MFMA GEMM + SiLU -> h (bf16) ----------------
// Block tile 128x64(x2), BK=64, 32KB LDS, m97 schedule; 8 waves x (32x32) wave-tiles:
// halves acc VGPR/wave -> more resident waves/CU to hide the staging drain.
__global__ __launch_bounds__(512)
void gateup_all(const u16* __restrict__ Xb,
                const u16* __restrict__ WgT, const u16* __restrict__ WuT,     // [E,I,H]
                const u16* __restrict__ sWgT, const u16* __restrict__ sWuT,   // [I,H]
                u16* __restrict__ hs,   // [T,I]
                u16* __restrict__ hp,   // [2T,I] contiguous per expert
                const int* __restrict__ counts,
                const int* __restrict__ pair_id)
{
    const int z = blockIdx.z;
    const bool SH = (z == 0);
    const int e = z - 1;
    const int nrows = SH ? T_TOK : counts[e];
    const int bm0 = blockIdx.y * 128;
    if (bm0 >= nrows) return;
    const int bn0 = blockIdx.x * 64;
    const u16* wgT = SH ? sWgT : WgT + (size_t)e * HDIM * IDIM;
    const u16* wuT = SH ? sWuT : WuT + (size_t)e * HDIM * IDIM;
    const int* plist = SH ? nullptr : (pair_id + e * T_TOK);
    u16* hout = SH ? hs : hp;

    int ebase = 0;
    if (!SH) {
#pragma unroll
        for (int i = 0; i < NEXP; ++i) ebase += (i < e) ? counts[i] : 0;
    }

    __shared__ __attribute__((aligned(16))) short As[128 * 64];  // 16 KB
    __shared__ __attribute__((aligned(16))) short Bg[64 * 64];   // 8 KB
    __shared__ __attribute__((aligned(16))) short Bu[64 * 64];   // 8 KB

    const int tid = threadIdx.x;
    const int lane = tid & 63;
    const int wid = tid >> 6;           // 0..7

    // A staging: 16 insts of 1024B (8 rows each); wave does insts wid*2, wid*2+1
    const char* aptr[2];
#pragma unroll
    for (int i = 0; i < 2; ++i) {
        int g = wid * 2 + i;
        int r = g * 8 + (lane >> 3);
        int row = bm0 + r;
        int srow;
        if (SH) srow = row;
        else    srow = (row < nrows) ? (plist[row] >> 1) : 0;
        int cslot = ((lane & 7) ^ (r & 7)) * 8;
        aptr[i] = (const char*)(Xb + (size_t)srow * HDIM + cslot);
    }
    // B staging: 8 insts each; wave does inst wid
    const char* bgptr; const char* buptr;
    {
        int r = wid * 8 + (lane >> 3);
        int nn = bn0 + r;
        int cslot = ((lane & 7) ^ (r & 7)) * 8;
        bgptr = (const char*)(wgT + (size_t)nn * HDIM + cslot);
        buptr = (const char*)(wuT + (size_t)nn * HDIM + cslot);
    }

    const int wm = wid & 3, wn = wid >> 2;    // 4 M-tiles x 2 N-tiles
    const int m0 = wm * 32, n0 = wn * 32;
    const int lr = lane & 15, lg = lane >> 4;

    f32x4 accg[2][2] = {};
    f32x4 accu[2][2] = {};

    for (int k0 = 0; k0 < HDIM; k0 += 64) {
#pragma unroll
        for (int i = 0; i < 2; ++i) {
            GLD16(aptr[i], (char*)As + (wid * 2 + i) * 1024);
            aptr[i] += 128;
        }
        GLD16(bgptr, (char*)Bg + wid * 1024);
        GLD16(buptr, (char*)Bu + wid * 1024);
        bgptr += 128; buptr += 128;
        __syncthreads();
#pragma unroll
        for (int kk = 0; kk < 2; ++kk) {
            short8 af[2], bgf[2], buf_[2];
#pragma unroll
            for (int mf = 0; mf < 2; ++mf) {
                int row = m0 + mf * 16 + lr;
                int slot = (kk * 4 + lg) ^ (row & 7);
                af[mf] = *(const short8*)((const char*)As + row * 128 + slot * 16);
            }
#pragma unroll
            for (int nf = 0; nf < 2; ++nf) {
                int row = n0 + nf * 16 + lr;
                int slot = (kk * 4 + lg) ^ (row & 7);
                bgf[nf]  = *(const short8*)((const char*)Bg + row * 128 + slot * 16);
                buf_[nf] = *(const short8*)((const char*)Bu + row * 128 + slot * 16);
            }
#pragma unroll
            for (int mf = 0; mf < 2; ++mf)
#pragma unroll
                for (int nf = 0; nf < 2; ++nf) {
                    accg[mf][nf] = __builtin_amdgcn_mfma_f32_16x16x32_bf16(af[mf], bgf[nf],  accg[mf][nf], 0, 0, 0);
                    accu[mf][nf] = __builtin_amdgcn_mfma_f32_16x16x32_bf16(af[mf], buf_[nf], accu[mf][nf], 0, 0, 0);
                }
        }
        __syncthreads();
    }

    // epilogue: C/D layout col=lane&15, row=4*(lane>>4)+reg
#pragma unroll
    for (int mf = 0; mf < 2; ++mf) {
#pragma unroll
        for (int j = 0; j < 4; ++j) {
            int row = bm0 + m0 + mf * 16 + lg * 4 + j;
            if (row >= nrows) continue;
            int outrow = SH ? row : (ebase + row);   // contiguous per expert
            u16* dst = hout + (size_t)outrow * IDIM + bn0 + n0 + lr;
#pragma unroll
            for (int nf = 0; nf < 2; ++nf) {
                float g = accg[mf][nf][j], u = accu[mf][nf][j];
                float sg = g / (1.f + __expf(-g));
                dst[nf * 16] = f2bf(sg * u);
            }
        }
    }
}

// ---------------- routed down: contiguous A rows; slot0 -> y0, slot1 -> y1 (bf16) ----------------
// Block tile 128x128, 8 waves x (32x64) wave-tiles.
__global__ __launch_bounds__(512)
void down_routed(const u16* __restrict__ Hp,      // [2T,I] contiguous per expert
                 const u16* __restrict__ WdT,     // [E,H,I]
                 u16* __restrict__ y0,            // [T,H]
                 u16* __restrict__ y1,            // [T,H]
                 const float* __restrict__ wpair,
                 const int* __restrict__ counts,
                 const int* __restrict__ pair_id)
{
    const int e = blockIdx.z;
    const int nrows = counts[e];
    const int bm0 = blockIdx.y * 128;
    if (bm0 >= nrows) return;
    const int bn0 = blockIdx.x * 128;
    const u16* wdT = WdT + (size_t)e * HDIM * IDIM;
    const int* plist = pair_id + e * T_TOK;

    int ebase = 0;
#pragma unroll
    for (int i = 0; i < NEXP; ++i) ebase += (i < e) ? counts[i] : 0;

    __shared__ __attribute__((aligned(16))) short As[128 * 64];  // 16 KB
    __shared__ __attribute__((aligned(16))) short Bs[128 * 64];  // 16 KB

    const int tid = threadIdx.x;
    const int lane = tid & 63;
    const int wid = tid >> 6;

    const char* aptr[2]; const char* bptr[2];
#pragma unroll
    for (int i = 0; i < 2; ++i) {
        int g = wid * 2 + i;
        int r = g * 8 + (lane >> 3);
        int row = bm0 + r;
        int srow = ebase + ((row < nrows) ? row : 0);   // contiguous stream
        int cslot = ((lane & 7) ^ (r & 7)) * 8;
        aptr[i] = (const char*)(Hp + (size_t)srow * IDIM + cslot);
        bptr[i] = (const char*)(wdT + (size_t)(bn0 + r) * IDIM + cslot);
    }

    const int wm = wid & 3, wn = wid >> 2;    // 4 M-tiles x 2 N-tiles
    const int m0 = wm * 32, n0 = wn * 64;
    const int lr = lane & 15, lg = lane >> 4;

    f32x4 acc[2][4] = {};

    for (int k0 = 0; k0 < IDIM; k0 += 64) {
#pragma unroll
        for (int i = 0; i < 2; ++i) {
            GLD16(aptr[i], (char*)As + (wid * 2 + i) * 1024);
            GLD16(bptr[i], (char*)Bs + (wid * 2 + i) * 1024);
            aptr[i] += 128; bptr[i] += 128;
        }
        __syncthreads();
#pragma unroll
        for (int kk = 0; kk < 2; ++kk) {
            short8 af[2], bf[4];
#pragma unroll
            for (int mf = 0; mf < 2; ++mf) {
                int row = m0 + mf * 16 + lr;
                int slot = (kk * 4 + lg) ^ (row & 7);
                af[mf] = *(const short8*)((const char*)As + row * 128 + slot * 16);
            }
#pragma unroll
            for (int nf = 0; nf < 4; ++nf) {
                int row = n0 + nf * 16 + lr;
                int slot = (kk * 4 + lg) ^ (row & 7);
                bf[nf] = *(const short8*)((const char*)Bs + row * 128 + slot * 16);
            }
#pragma unroll
            for (int mf = 0; mf < 2; ++mf)
#pragma unroll
                for (int nf = 0; nf < 4; ++nf)
                    acc[mf][nf] = __builtin_amdgcn_mfma_f32_16x16x32_bf16(af[mf], bf[nf], acc[mf][nf], 0, 0, 0);
        }
        __syncthreads();
    }

#pragma unroll
    for (int mf = 0; mf < 2; ++mf) {
#pragma unroll
        for (int j = 0; j < 4; ++j) {
            int row = bm0 + m0 + mf * 16 + lg * 4 + j;
            if (row >= nrows) continue;
            int p = plist[row];
            int t = p >> 1;
            float w = wpair[p];
            u16* dst = ((p & 1) ? y1 : y0) + (size_t)t * HDIM + bn0 + n0 + lr;
#pragma unroll
            for (int nf = 0; nf < 4; ++nf)
                dst[nf * 16] = f2bf(acc[mf][nf][j] * w);
        }
    }
}

// ---------------- shared down + combine: out = hs@swd + y0 + y1 (write-only out) ----------------
__global__ __launch_bounds__(512)
void down_shared_combine(const u16* __restrict__ Hs,   // [T,I]
                         const u16* __restrict__ swdT, // [H,I]
                         const u16* __restrict__ y0,   // [T,H]
                         const u16* __restrict__ y1,   // [T,H]
                         float* __restrict__ out)      // [T,H]
{
    const int bm0 = blockIdx.y * 128;
    const int bn0 = blockIdx.x * 128;

    __shared__ __attribute__((aligned(16))) short As[128 * 64];
    __shared__ __attribute__((aligned(16))) short Bs[128 * 64];

    const int tid = threadIdx.x;
    const int lane = tid & 63;
    const int wid = tid >> 6;

    const char* aptr[2]; const char* bptr[2];
#pragma unroll
    for (int i = 0; i < 2; ++i) {
        int g = wid * 2 + i;
        int r = g * 8 + (lane >> 3);
        int cslot = ((lane & 7) ^ (r & 7)) * 8;
        aptr[i] = (const char*)(Hs + (size_t)(bm0 + r) * IDIM + cslot);
        bptr[i] = (const char*)(swdT + (size_t)(bn0 + r) * IDIM + cslot);
    }

    const int wm = wid & 3, wn = wid >> 2;
    const int m0 = wm * 32, n0 = wn * 64;
    const int lr = lane & 15, lg = lane >> 4;

    f32x4 acc[2][4] = {};

    for (int k0 = 0; k0 < IDIM; k0 += 64) {
#pragma unroll
        for (int i = 0; i < 2; ++i) {
            GLD16(aptr[i], (char*)As + (wid * 2 + i) * 1024);
            GLD16(bptr[i], (char*)Bs + (wid * 2 + i) * 1024);
            aptr[i] += 128; bptr[i] += 128;
        }
        __syncthreads();
#pragma unroll
        for (int kk = 0; kk < 2; ++kk) {
            short8 af[2], bf[4];
#pragma unroll
            for (int mf = 0; mf < 2; ++mf) {
                int row = m0 + mf * 16 + lr;
                int slot = (kk * 4 + lg) ^ (row & 7);
                af[mf] = *(const short8*)((const char*)As + row * 128 + slot * 16);
            }
#pragma unroll
            for (int nf = 0; nf < 4; ++nf) {
                int row = n0 + nf * 16 + lr;
                int slot = (kk * 4 + lg) ^ (row & 7);
                bf[nf] = *(const short8*)((const char*)Bs + row * 128 + slot * 16);
            }
#pragma unroll
            for (int mf = 0; mf < 2; ++mf)
#pragma unroll
                for (int nf = 0; nf < 4; ++nf)
                    acc[mf][nf] = __builtin_amdgcn_mfma_f32_16x16x32_bf16(af[mf], bf[nf], acc[mf][nf], 0, 0, 0);
        }
        __syncthreads();
    }

#pragma unroll
    for (int mf = 0; mf < 2; ++mf) {
#pragma unroll
        for (int j = 0; j < 4; ++j) {
            int t = bm0 + m0 + mf * 16 + lg * 4 + j;
            float* dst = out + (size_t)t * HDIM + bn0 + n0 + lr;
            const u16* y0src = y0 + (size_t)t * HDIM + bn0 + n0 + lr;
            const u16* y1src = y1 + (size_t)t * HDIM + bn0 + n0 + lr;
#pragma unroll
            for (int nf = 0; nf < 4; ++nf)
                dst[nf * 16] = acc[mf][nf][j] + bf2f(y0src[nf * 16]) + bf2f(y1src[nf * 16]);
        }
    }
}

extern "C" void kernel_launch(void* const* d_in, const int* in_sizes, int n_in,
                              void* d_out, int out_size, void* d_ws, size_t ws_size,
                              hipStream_t stream) {
    const float* X    = (const float*)d_in[0];
    const float* Wr   = (const float*)d_in[1];
    const float* bias = (const float*)d_in[2];
    const float* wg   = (const float*)d_in[3];
    const float* wu   = (const float*)d_in[4];
    const float* wdn  = (const float*)d_in[5];
    const float* swg  = (const float*)d_in[6];
    const float* swu  = (const float*)d_in[7];
    const float* swd  = (const float*)d_in[8];
    float* out = (float*)d_out;
    (void)in_sizes; (void)n_in; (void)out_size; (void)ws_size;

    char* ws = (char*)d_ws;
    const size_t MB = 1048576;
    int*   counts   = (int*)ws;                          // 32 B
    float* wpair    = (float*)(ws + 4096);               // 64 KB
    int*   pair_id  = (int*)(ws + 4096 + 65536);         // 256 KB
    int*   topk_ids = (int*)(ws + 524288);               // 32 KB
    u16* Xb   = (u16*)(ws + 1 * MB);                     // 16 MB [T,H]; y1 aliases after gateup
    u16* wgT  = (u16*)(ws + 17 * MB);                    // 8 MB [E,I,H]; y0 aliases wgT+wuT after gateup
    u16* wuT  = (u16*)(ws + 25 * MB);                    // 8 MB
    u16* wdnT = (u16*)(ws + 33 * MB);                    // 8 MB [E,H,I]
    u16* swgT = (u16*)(ws + 41 * MB);                    // 1 MB [I,H]
    u16* swuT = (u16*)(ws + 42 * MB);                    // 1 MB
    u16* swdT = (u16*)(ws + 43 * MB);                    // 1 MB [H,I]
    u16* hs   = (u16*)(ws + 44 * MB);                    // 8 MB [T,I]
    u16* hp   = (u16*)(ws + 52 * MB);                    // 16 MB [2T,I] contiguous per expert
    u16* y1   = Xb;                                      // Xb dead after gateup_all
    u16* y0   = wgT;                                     // wgT/wuT dead after gateup_all (16 MB span)

    // router (2048 blocks) + 27 weight transposes (3456 blocks) in one launch
    prologue<<<2048 + 27 * 128, 256, 0, stream>>>(
        X, Wr, bias, Xb, wpair, topk_ids,
        wg, wu, wdn, swg, swu, swd, wgT, wuT, wdnT, swgT, swuT, swdT);
    build_lists<<<NEXP, 256, 0, stream>>>(topk_ids, counts, pair_id);

    // col-block fastest (blockIdx.x) -> per-XCD weight-slice L2 reuse
    gateup_all<<<dim3(IDIM / 64, T_TOK / 128, NEXP + 1), 512, 0, stream>>>(
        Xb, wgT, wuT, swgT, swuT, hs, hp, counts, pair_id);

    down_routed<<<dim3(HDIM / 128, T_TOK / 128, NEXP), 512, 0, stream>>>(
        hp, wdnT, y0, y1, wpair, counts, pair_id);

    down_shared_combine<<<dim3(HDIM / 128, T_TOK / 128, 1), 512, 0, stream>>>(
        hs, swdT, y0, y1, out);
}